// Round 6
// baseline (656.623 us; speedup 1.0000x reference)
//
#include <hip/hip_runtime.h>
#include <math.h>

#define HID 32
#define HOR 12
#define NBLK 128          // edge-chunk blocks for count/scatter
#define BSH 5             // 32 nodes per bucket
#define BNODES 32
#define MAXBK 2048        // max buckets (requires N <= 65536 and nbk <= MAXBK)

__device__ __forceinline__ float sigmoidf_(float x) { return 1.0f / (1.0f + expf(-x)); }

// K1: per-chunk histograms by src-bucket and dst-bucket (LDS atomics only)
__global__ __launch_bounds__(256) void k_count(const int* __restrict__ src,
    const int* __restrict__ dst, int E, int chunk, int nbk,
    int* __restrict__ histS, int* __restrict__ histD) {
    __shared__ int hs[MAXBK], hd[MAXBK];
    int t = threadIdx.x;
    for (int c = t; c < nbk; c += 256) { hs[c] = 0; hd[c] = 0; }
    __syncthreads();
    int beg = blockIdx.x * chunk, end = min(beg + chunk, E);
    for (int i = beg + t; i < end; i += 256) {
        atomicAdd(&hs[src[i] >> BSH], 1);
        atomicAdd(&hd[dst[i] >> BSH], 1);
    }
    __syncthreads();
    size_t rb = (size_t)blockIdx.x * nbk;
    for (int c = t; c < nbk; c += 256) { histS[rb + c] = hs[c]; histD[rb + c] = hd[c]; }
}

// K2a: in-place column exclusive prefix over chunk-blocks; emit column totals
__global__ void k_colscan(int* __restrict__ histS, int* __restrict__ histD,
                          int* __restrict__ totS, int* __restrict__ totD, int nbk) {
    int table = blockIdx.x & 1;
    int col = (blockIdx.x >> 1) * 256 + threadIdx.x;
    if (col >= nbk) return;
    int* h  = table ? histD : histS;
    int* tt = table ? totD : totS;
    int run = 0;
    for (int b = 0; b < NBLK; ++b) {
        size_t idx = (size_t)b * nbk + col;
        int v = h[idx]; h[idx] = run; run += v;
    }
    tt[col] = run;
}

// K2b: exclusive scan of bucket totals -> baseS/baseD (nbk+1 entries each)
__global__ __launch_bounds__(256) void k_bucketbase(const int* __restrict__ totS,
    const int* __restrict__ totD, int* __restrict__ baseS, int* __restrict__ baseD, int nbk) {
    __shared__ int ss[256];
    int t = threadIdx.x;
    for (int table = 0; table < 2; ++table) {
        const int* tot = table ? totD : totS;
        int* base = table ? baseD : baseS;
        int a[8]; int tsum = 0;
        #pragma unroll
        for (int k2 = 0; k2 < 8; ++k2) {
            int i = t * 8 + k2;
            a[k2] = (i < nbk) ? tot[i] : 0;
            tsum += a[k2];
        }
        ss[t] = tsum; __syncthreads();
        for (int off = 1; off < 256; off <<= 1) {
            int v = (t >= off) ? ss[t - off] : 0;
            __syncthreads(); ss[t] += v; __syncthreads();
        }
        int run = ss[t] - tsum;
        #pragma unroll
        for (int k2 = 0; k2 < 8; ++k2) {
            int i = t * 8 + k2;
            if (i <= nbk) base[i] = run;
            run += a[k2];
        }
        __syncthreads();
    }
}

// flag = 1 if any h0 element nonzero
__global__ void k_hflag(const float* __restrict__ h0, int* __restrict__ flag, int total) {
    int i = blockIdx.x * 256 + threadIdx.x;
    float v = (i < total) ? h0[i] : 0.0f;
    if (__ballot(v != 0.0f)) {
        if ((threadIdx.x & 63) == 0) atomicOr(flag, 1);
    }
}

// K3: scatter edges into exact reserved slots; LDS cursors only, plain global stores
__global__ __launch_bounds__(256) void k_scatter2(const int* __restrict__ src,
    const int* __restrict__ dst, const float* __restrict__ w, int E, int chunk, int nbk,
    const int* __restrict__ histS, const int* __restrict__ histD,
    const int* __restrict__ baseS, const int* __restrict__ baseD,
    int2* __restrict__ srcBins, int2* __restrict__ dstBins) {
    __shared__ int curS[MAXBK], curD[MAXBK];
    int t = threadIdx.x;
    size_t rb = (size_t)blockIdx.x * nbk;
    for (int c = t; c < nbk; c += 256) {
        curS[c] = baseS[c] + histS[rb + c];
        curD[c] = baseD[c] + histD[rb + c];
    }
    __syncthreads();
    int beg = blockIdx.x * chunk, end = min(beg + chunk, E);
    for (int i = beg + t; i < end; i += 256) {
        int s = src[i], d = dst[i];
        float wv = w[i];
        int ps = atomicAdd(&curS[s >> BSH], 1);
        srcBins[ps] = make_int2(s, __float_as_int(wv));
        int pd = atomicAdd(&curD[d >> BSH], 1);
        dstBins[pd] = make_int2(s | ((d & (BNODES - 1)) << 16), __float_as_int(wv));
    }
}

// K4: per src-bucket: deg in LDS (ds_add_f32) -> dinv coalesced
__global__ __launch_bounds__(256) void k_deg(const int2* __restrict__ srcBins,
    const int* __restrict__ baseS, float* __restrict__ dinv, int N) {
    __shared__ float dg[BNODES];
    int t = threadIdx.x, b = blockIdx.x;
    if (t < BNODES) dg[t] = 0.0f;
    __syncthreads();
    int beg = baseS[b], end = baseS[b + 1];
    for (int i = beg + t; i < end; i += 256) {
        int2 r = srcBins[i];
        atomicAdd(&dg[r.x & (BNODES - 1)], __int_as_float(r.y));
    }
    __syncthreads();
    if (t < BNODES) {
        int n = (b << BSH) + t;
        if (n < N) { float s = dg[t]; dinv[n] = (s > 0.0f) ? rsqrtf(s) : 0.0f; }
    }
}

// K5: flat streaming: dstBins.y <- -w * dinv[src]. dinv (200 KB) is L2-resident;
// 6250 independent blocks, shallow work -> latency fully hidden.
__global__ __launch_bounds__(256) void k_fold(int2* __restrict__ dstBins,
    const float* __restrict__ dinv, int E) {
    int e = blockIdx.x * 256 + threadIdx.x;
    if (e >= E) return;
    int2 r = dstBins[e];
    float nws = -__int_as_float(r.y) * dinv[r.x & 0xFFFF];
    dstBins[e].y = __float_as_int(nws);
}

// K6: per dst-bucket, 1024 threads = 32 groups x 32 feats. Depth-2 software
// pipeline: record prefetched 2 iters ahead, X value 1 iter ahead — cross-
// iteration dataflow forces registers to stay live (defeats the 16-VGPR
// serialization seen in R5). dinv[d] applied at writeback (constant per row).
__global__ __launch_bounds__(1024) void k_acc(const int2* __restrict__ dstBins,
    const int* __restrict__ baseD, const float* __restrict__ dinv,
    const float* __restrict__ X, const float* __restrict__ H0,
    const int* __restrict__ hflag,
    float* __restrict__ LX, float* __restrict__ LH, int N) {
    __shared__ float lx[BNODES * HID], lh[BNODES * HID];
    int t = threadIdx.x, b = blockIdx.x;
    lx[t] = 0.0f; lh[t] = 0.0f;
    __syncthreads();
    int f = t & 31, g = t >> 5;          // 32 groups
    int beg = baseD[b], end = baseD[b + 1];
    bool hf = (*hflag != 0);
    int i0 = beg + g;
    if (i0 < end) {
        if (!hf) {
            int2 r = dstBins[i0];
            int ip = i0 + 32;
            bool has_n = ip < end;
            int2 rn = has_n ? dstBins[ip] : r;
            float xv = X[((r.x & 0xFFFF) << 5) + f];
            while (has_n) {
                int inn = ip + 32;
                bool has_nn = inn < end;
                int2 rnn = has_nn ? dstBins[inn] : rn;      // prefetch rec (2 ahead)
                float xn = X[((rn.x & 0xFFFF) << 5) + f];   // prefetch X (1 ahead)
                atomicAdd(&lx[((r.x >> 16) << 5) + f], __int_as_float(r.y) * xv);
                r = rn; xv = xn; rn = rnn; ip = inn; has_n = has_nn;
            }
            atomicAdd(&lx[((r.x >> 16) << 5) + f], __int_as_float(r.y) * xv);
        } else {
            int2 r = dstBins[i0];
            int ip = i0 + 32;
            bool has_n = ip < end;
            int2 rn = has_n ? dstBins[ip] : r;
            float xv = X[((r.x & 0xFFFF) << 5) + f];
            float hv = H0[((r.x & 0xFFFF) << 5) + f];
            while (has_n) {
                int inn = ip + 32;
                bool has_nn = inn < end;
                int2 rnn = has_nn ? dstBins[inn] : rn;
                float xn = X[((rn.x & 0xFFFF) << 5) + f];
                float hn = H0[((rn.x & 0xFFFF) << 5) + f];
                float wv = __int_as_float(r.y);
                atomicAdd(&lx[((r.x >> 16) << 5) + f], wv * xv);
                atomicAdd(&lh[((r.x >> 16) << 5) + f], wv * hv);
                r = rn; xv = xn; hv = hn; rn = rnn; ip = inn; has_n = has_nn;
            }
            float wv = __int_as_float(r.y);
            atomicAdd(&lx[((r.x >> 16) << 5) + f], wv * xv);
            atomicAdd(&lh[((r.x >> 16) << 5) + f], wv * hv);
        }
    }
    __syncthreads();
    // writeback: thread t owns one tile element; fold in dinv[dst]
    int n = (b << BSH) + (t >> 5);
    if (n < N) {
        float dv = dinv[n];
        LX[(n << 5) + f] = dv * lx[t];
        LH[(n << 5) + f] = dv * lh[t];
    }
}

// Per (node n, out-feature j): 4 gates fused LSTM cell
__global__ __launch_bounds__(256) void k_gates(
    const float* __restrict__ X, const float* __restrict__ LX,
    const float* __restrict__ H0, const float* __restrict__ LH,
    const float* __restrict__ C0,
    const float* __restrict__ Wx, const float* __restrict__ bx,
    const float* __restrict__ Wh, const float* __restrict__ bh,
    const float* __restrict__ wc, const float* __restrict__ b,
    float* __restrict__ outH, float* __restrict__ outC, int N) {
    int tid = blockIdx.x * 256 + threadIdx.x;
    int n = tid >> 5;
    int j = tid & 31;
    if (n >= N) return;

    int base = n << 5;
    float xk  = X[base + j];
    float lxk = LX[base + j];
    float hk  = H0[base + j];
    float lhk = LH[base + j];

    float pre0 = bx[0 * HID + j] + bh[0 * HID + j] + b[0 * HID + j];
    float pre1 = bx[1 * HID + j] + bh[1 * HID + j] + b[1 * HID + j];
    float pre2 = bx[2 * HID + j] + bh[2 * HID + j] + b[2 * HID + j];
    float pre3 = bx[3 * HID + j] + bh[3 * HID + j] + b[3 * HID + j];

    #pragma unroll 8
    for (int k = 0; k < HID; ++k) {
        float xv  = __shfl(xk, k, 32);
        float lxv = __shfl(lxk, k, 32);
        float hv  = __shfl(hk, k, 32);
        float lhv = __shfl(lhk, k, 32);
        int row = k * HID + j;
        pre0 += xv * Wx[0 * 2048 + row] + lxv * Wx[0 * 2048 + 1024 + row]
              + hv * Wh[0 * 2048 + row] + lhv * Wh[0 * 2048 + 1024 + row];
        pre1 += xv * Wx[1 * 2048 + row] + lxv * Wx[1 * 2048 + 1024 + row]
              + hv * Wh[1 * 2048 + row] + lhv * Wh[1 * 2048 + 1024 + row];
        pre2 += xv * Wx[2 * 2048 + row] + lxv * Wx[2 * 2048 + 1024 + row]
              + hv * Wh[2 * 2048 + row] + lhv * Wh[2 * 2048 + 1024 + row];
        pre3 += xv * Wx[3 * 2048 + row] + lxv * Wx[3 * 2048 + 1024 + row]
              + hv * Wh[3 * 2048 + row] + lhv * Wh[3 * 2048 + 1024 + row];
    }

    float c0v = C0[base + j];
    float I  = sigmoidf_(pre0 + wc[0 * HID + j] * c0v);
    float Fg = sigmoidf_(pre1 + wc[1 * HID + j] * c0v);
    float T  = tanhf(pre2);
    float C  = Fg * c0v + I * T;
    float O  = sigmoidf_(pre3 + wc[2 * HID + j] * C);
    float H  = O * tanhf(C);

    outH[base + j] = H;
    outC[base + j] = C;
}

// h[n,t] = b_lin[t] + sum_k relu(H[n,k]) * W_lin[k,t]
__global__ void k_head(const float* __restrict__ H, const float* __restrict__ Wl,
                       const float* __restrict__ bl, float* __restrict__ hout, int N) {
    int tid = blockIdx.x * 256 + threadIdx.x;
    int n = tid / HOR;
    int t = tid - n * HOR;
    if (n >= N) return;
    float acc = bl[t];
    #pragma unroll
    for (int k = 0; k < HID; ++k) {
        float v = H[(n << 5) + k];
        acc += fmaxf(v, 0.0f) * Wl[k * HOR + t];
    }
    hout[n * HOR + t] = acc;
}

extern "C" void kernel_launch(void* const* d_in, const int* in_sizes, int n_in,
                              void* d_out, int out_size, void* d_ws, size_t ws_size,
                              hipStream_t stream) {
    const float* x  = (const float*)d_in[0];
    const int*   ei = (const int*)d_in[1];
    const float* ew = (const float*)d_in[2];
    const float* Wx = (const float*)d_in[3];
    const float* bx = (const float*)d_in[4];
    const float* Wh = (const float*)d_in[5];
    const float* bh = (const float*)d_in[6];
    const float* wc = (const float*)d_in[7];
    const float* b  = (const float*)d_in[8];
    const float* Wl = (const float*)d_in[9];
    const float* bl = (const float*)d_in[10];
    const float* h0 = (const float*)d_in[11];
    const float* c0 = (const float*)d_in[12];

    int N = in_sizes[0] / HID;      // x is (N,1,32)
    int E = in_sizes[2];            // edge_weight is (E,)
    const int* src = ei;
    const int* dst = ei + E;
    int nbk = (N + BNODES - 1) >> BSH;          // 1563 for N=50000 (< MAXBK)
    int chunk = (E + NBLK - 1) / NBLK;

    // workspace (int units):
    // [dstBins 2E][srcBins region: max(2E, 2*N*32) — srcBins aliased by LX/LH]
    // [histS NBLK*nbk][histD NBLK*nbk][totS MAXBK][totD MAXBK]
    // [baseS MAXBK+1][baseD MAXBK+1][dinv N][flag 1]
    int* wsi = (int*)d_ws;
    size_t regionB = (size_t)2 * E;
    size_t regionL = (size_t)2 * N * HID;
    size_t region  = regionB > regionL ? regionB : regionL;

    int2*  dstBins = (int2*)wsi;
    int2*  srcBins = (int2*)(wsi + (size_t)2 * E);
    float* LX      = (float*)srcBins;                // aliases srcBins (dead after k_deg)
    float* LH      = LX + (size_t)N * HID;
    int*   histS   = wsi + (size_t)2 * E + region;
    int*   histD   = histS + (size_t)NBLK * nbk;
    int*   totS    = histD + (size_t)NBLK * nbk;
    int*   totD    = totS + MAXBK;
    int*   baseS   = totD + MAXBK;
    int*   baseD   = baseS + (MAXBK + 1);
    float* dinv    = (float*)(baseD + (MAXBK + 1));
    int*   flag    = (int*)(dinv + N);

    float* hOut = (float*)d_out;            // (N,12)
    float* HOut = hOut + (size_t)N * HOR;   // (N,32)
    float* COut = HOut + (size_t)N * HID;   // (N,32)

    hipMemsetAsync(flag, 0, sizeof(int), stream);

    k_count<<<NBLK, 256, 0, stream>>>(src, dst, E, chunk, nbk, histS, histD);
    k_colscan<<<2 * ((nbk + 255) / 256), 256, 0, stream>>>(histS, histD, totS, totD, nbk);
    k_bucketbase<<<1, 256, 0, stream>>>(totS, totD, baseS, baseD, nbk);
    k_hflag<<<(N * HID + 255) / 256, 256, 0, stream>>>(h0, flag, N * HID);

    k_scatter2<<<NBLK, 256, 0, stream>>>(src, dst, ew, E, chunk, nbk,
                                         histS, histD, baseS, baseD, srcBins, dstBins);

    k_deg<<<nbk, 256, 0, stream>>>(srcBins, baseS, dinv, N);

    k_fold<<<(E + 255) / 256, 256, 0, stream>>>(dstBins, dinv, E);

    k_acc<<<nbk, 1024, 0, stream>>>(dstBins, baseD, dinv, x, h0, flag, LX, LH, N);

    k_gates<<<(N * HID + 255) / 256, 256, 0, stream>>>(x, LX, h0, LH, c0,
                                                       Wx, bx, Wh, bh, wc, b,
                                                       HOut, COut, N);

    k_head<<<(N * HOR + 255) / 256, 256, 0, stream>>>(HOut, Wl, bl, hOut, N);
}

// Round 7
// 628.827 us; speedup vs baseline: 1.0442x; 1.0442x over previous
//
#include <hip/hip_runtime.h>
#include <math.h>

#define HID 32
#define HOR 12
#define NBLK 128          // edge-chunk blocks for count/scatter
#define BSH 5             // 32 nodes per bucket
#define BNODES 32
#define MAXBK 2048        // max buckets (requires N <= 65536 and nbk <= MAXBK)
#define LSTR 33           // LDS row stride (+1 pad: spreads banks by dst-local id)

__device__ __forceinline__ float sigmoidf_(float x) { return 1.0f / (1.0f + expf(-x)); }

// K1: per-chunk histograms by src-bucket and dst-bucket (LDS atomics only)
__global__ __launch_bounds__(256) void k_count(const int* __restrict__ src,
    const int* __restrict__ dst, int E, int chunk, int nbk,
    int* __restrict__ histS, int* __restrict__ histD) {
    __shared__ int hs[MAXBK], hd[MAXBK];
    int t = threadIdx.x;
    for (int c = t; c < nbk; c += 256) { hs[c] = 0; hd[c] = 0; }
    __syncthreads();
    int beg = blockIdx.x * chunk, end = min(beg + chunk, E);
    for (int i = beg + t; i < end; i += 256) {
        atomicAdd(&hs[src[i] >> BSH], 1);
        atomicAdd(&hd[dst[i] >> BSH], 1);
    }
    __syncthreads();
    size_t rb = (size_t)blockIdx.x * nbk;
    for (int c = t; c < nbk; c += 256) { histS[rb + c] = hs[c]; histD[rb + c] = hd[c]; }
}

// K2a: in-place column exclusive prefix over chunk-blocks; emit column totals
__global__ void k_colscan(int* __restrict__ histS, int* __restrict__ histD,
                          int* __restrict__ totS, int* __restrict__ totD, int nbk) {
    int table = blockIdx.x & 1;
    int col = (blockIdx.x >> 1) * 256 + threadIdx.x;
    if (col >= nbk) return;
    int* h  = table ? histD : histS;
    int* tt = table ? totD : totS;
    int run = 0;
    for (int b = 0; b < NBLK; ++b) {
        size_t idx = (size_t)b * nbk + col;
        int v = h[idx]; h[idx] = run; run += v;
    }
    tt[col] = run;
}

// K2b: exclusive scan of bucket totals -> baseS/baseD (nbk+1 entries each)
__global__ __launch_bounds__(256) void k_bucketbase(const int* __restrict__ totS,
    const int* __restrict__ totD, int* __restrict__ baseS, int* __restrict__ baseD, int nbk) {
    __shared__ int ss[256];
    int t = threadIdx.x;
    for (int table = 0; table < 2; ++table) {
        const int* tot = table ? totD : totS;
        int* base = table ? baseD : baseS;
        int a[8]; int tsum = 0;
        #pragma unroll
        for (int k2 = 0; k2 < 8; ++k2) {
            int i = t * 8 + k2;
            a[k2] = (i < nbk) ? tot[i] : 0;
            tsum += a[k2];
        }
        ss[t] = tsum; __syncthreads();
        for (int off = 1; off < 256; off <<= 1) {
            int v = (t >= off) ? ss[t - off] : 0;
            __syncthreads(); ss[t] += v; __syncthreads();
        }
        int run = ss[t] - tsum;
        #pragma unroll
        for (int k2 = 0; k2 < 8; ++k2) {
            int i = t * 8 + k2;
            if (i <= nbk) base[i] = run;
            run += a[k2];
        }
        __syncthreads();
    }
}

// flag = 1 if any h0 element nonzero
__global__ void k_hflag(const float* __restrict__ h0, int* __restrict__ flag, int total) {
    int i = blockIdx.x * 256 + threadIdx.x;
    float v = (i < total) ? h0[i] : 0.0f;
    if (__ballot(v != 0.0f)) {
        if ((threadIdx.x & 63) == 0) atomicOr(flag, 1);
    }
}

// K3: scatter edges into exact reserved slots; LDS cursors only, plain global stores
__global__ __launch_bounds__(256) void k_scatter2(const int* __restrict__ src,
    const int* __restrict__ dst, const float* __restrict__ w, int E, int chunk, int nbk,
    const int* __restrict__ histS, const int* __restrict__ histD,
    const int* __restrict__ baseS, const int* __restrict__ baseD,
    int2* __restrict__ srcBins, int2* __restrict__ dstBins) {
    __shared__ int curS[MAXBK], curD[MAXBK];
    int t = threadIdx.x;
    size_t rb = (size_t)blockIdx.x * nbk;
    for (int c = t; c < nbk; c += 256) {
        curS[c] = baseS[c] + histS[rb + c];
        curD[c] = baseD[c] + histD[rb + c];
    }
    __syncthreads();
    int beg = blockIdx.x * chunk, end = min(beg + chunk, E);
    for (int i = beg + t; i < end; i += 256) {
        int s = src[i], d = dst[i];
        float wv = w[i];
        int ps = atomicAdd(&curS[s >> BSH], 1);
        srcBins[ps] = make_int2(s, __float_as_int(wv));
        int pd = atomicAdd(&curD[d >> BSH], 1);
        dstBins[pd] = make_int2(s | ((d & (BNODES - 1)) << 16), __float_as_int(wv));
    }
}

// K4: per src-bucket: deg in LDS (ds_add_f32) -> dinv coalesced
__global__ __launch_bounds__(256) void k_deg(const int2* __restrict__ srcBins,
    const int* __restrict__ baseS, float* __restrict__ dinv, int N) {
    __shared__ float dg[BNODES];
    int t = threadIdx.x, b = blockIdx.x;
    if (t < BNODES) dg[t] = 0.0f;
    __syncthreads();
    int beg = baseS[b], end = baseS[b + 1];
    for (int i = beg + t; i < end; i += 256) {
        int2 r = srcBins[i];
        atomicAdd(&dg[r.x & (BNODES - 1)], __int_as_float(r.y));
    }
    __syncthreads();
    if (t < BNODES) {
        int n = (b << BSH) + t;
        if (n < N) { float s = dg[t]; dinv[n] = (s > 0.0f) ? rsqrtf(s) : 0.0f; }
    }
}

// K5: flat streaming: dstBins.y <- -w * dinv[src] (dinv is L2-resident)
__global__ __launch_bounds__(256) void k_fold(int2* __restrict__ dstBins,
    const float* __restrict__ dinv, int E) {
    int e = blockIdx.x * 256 + threadIdx.x;
    if (e >= E) return;
    int2 r = dstBins[e];
    float nws = -__int_as_float(r.y) * dinv[r.x & 0xFFFF];
    dstBins[e].y = __float_as_int(nws);
}

// K6: per dst-bucket. 256 threads = 32 edge-slots x 8 feature-quads.
// Records staged to LDS in 256-edge chunks; each thread then issues 8
// INDEPENDENT float4 X-row loads (hoisted, unrolled) before consuming any —
// ~128B in flight per thread. LDS accumulate with stride-33 rows to spread
// banks by dst-local id. dinv[d] folded at writeback.
__global__ __launch_bounds__(256) void k_acc(const int2* __restrict__ dstBins,
    const int* __restrict__ baseD, const float* __restrict__ dinv,
    const float* __restrict__ X, const float* __restrict__ H0,
    const int* __restrict__ hflag,
    float* __restrict__ LX, float* __restrict__ LH, int N) {
    __shared__ float lx[BNODES * LSTR];
    __shared__ float lh[BNODES * LSTR];
    __shared__ int2  rec[256];
    __shared__ float dv[BNODES];
    int t = threadIdx.x, b = blockIdx.x;
    for (int i = t; i < BNODES * LSTR; i += 256) { lx[i] = 0.0f; lh[i] = 0.0f; }
    if (t < BNODES) {
        int n = (b << BSH) + t;
        dv[t] = (n < N) ? dinv[n] : 0.0f;
    }
    int beg = baseD[b], end = baseD[b + 1];
    bool hf = (*hflag != 0);
    const float4* X4 = (const float4*)X;
    const float4* H4 = (const float4*)H0;
    int slot = t >> 3;          // 0..31 edge slot
    int qi = t & 7;             // feature quad
    int fb = qi << 2;           // feature base
    __syncthreads();

    for (int cs = beg; cs < end; cs += 256) {
        int m = end - cs; if (m > 256) m = 256;
        // stage records (coalesced)
        if (t < m) rec[t] = dstBins[cs + t];
        __syncthreads();

        int2 r[8]; bool val[8];
        #pragma unroll
        for (int p = 0; p < 8; ++p) {
            int ei = (p << 5) + slot;
            val[p] = ei < m;
            r[p] = val[p] ? rec[ei] : make_int2(0, 0);
        }
        float4 xv[8];
        #pragma unroll
        for (int p = 0; p < 8; ++p) {
            int s = r[p].x & 0xFFFF;
            xv[p] = val[p] ? X4[(s << 3) + qi] : make_float4(0.f, 0.f, 0.f, 0.f);
        }
        if (hf) {
            float4 hv[8];
            #pragma unroll
            for (int p = 0; p < 8; ++p) {
                int s = r[p].x & 0xFFFF;
                hv[p] = val[p] ? H4[(s << 3) + qi] : make_float4(0.f, 0.f, 0.f, 0.f);
            }
            #pragma unroll
            for (int p = 0; p < 8; ++p) {
                if (val[p]) {
                    float w = __int_as_float(r[p].y);
                    int lb = (r[p].x >> 16) * LSTR + fb;
                    atomicAdd(&lx[lb + 0], w * xv[p].x);
                    atomicAdd(&lx[lb + 1], w * xv[p].y);
                    atomicAdd(&lx[lb + 2], w * xv[p].z);
                    atomicAdd(&lx[lb + 3], w * xv[p].w);
                    atomicAdd(&lh[lb + 0], w * hv[p].x);
                    atomicAdd(&lh[lb + 1], w * hv[p].y);
                    atomicAdd(&lh[lb + 2], w * hv[p].z);
                    atomicAdd(&lh[lb + 3], w * hv[p].w);
                }
            }
        } else {
            #pragma unroll
            for (int p = 0; p < 8; ++p) {
                if (val[p]) {
                    float w = __int_as_float(r[p].y);
                    int lb = (r[p].x >> 16) * LSTR + fb;
                    atomicAdd(&lx[lb + 0], w * xv[p].x);
                    atomicAdd(&lx[lb + 1], w * xv[p].y);
                    atomicAdd(&lx[lb + 2], w * xv[p].z);
                    atomicAdd(&lx[lb + 3], w * xv[p].w);
                }
            }
        }
        __syncthreads();   // protect rec[] before next chunk's restage
    }

    // writeback: fold dinv[dst]
    for (int i = t; i < BNODES * HID; i += 256) {
        int dl = i >> 5, f = i & 31;
        int n = (b << BSH) + dl;
        if (n < N) {
            float dvv = dv[dl];
            LX[(n << 5) + f] = dvv * lx[dl * LSTR + f];
            LH[(n << 5) + f] = dvv * lh[dl * LSTR + f];
        }
    }
}

// Per (node n, out-feature j): 4 gates fused LSTM cell
__global__ __launch_bounds__(256) void k_gates(
    const float* __restrict__ X, const float* __restrict__ LX,
    const float* __restrict__ H0, const float* __restrict__ LH,
    const float* __restrict__ C0,
    const float* __restrict__ Wx, const float* __restrict__ bx,
    const float* __restrict__ Wh, const float* __restrict__ bh,
    const float* __restrict__ wc, const float* __restrict__ b,
    float* __restrict__ outH, float* __restrict__ outC, int N) {
    int tid = blockIdx.x * 256 + threadIdx.x;
    int n = tid >> 5;
    int j = tid & 31;
    if (n >= N) return;

    int base = n << 5;
    float xk  = X[base + j];
    float lxk = LX[base + j];
    float hk  = H0[base + j];
    float lhk = LH[base + j];

    float pre0 = bx[0 * HID + j] + bh[0 * HID + j] + b[0 * HID + j];
    float pre1 = bx[1 * HID + j] + bh[1 * HID + j] + b[1 * HID + j];
    float pre2 = bx[2 * HID + j] + bh[2 * HID + j] + b[2 * HID + j];
    float pre3 = bx[3 * HID + j] + bh[3 * HID + j] + b[3 * HID + j];

    #pragma unroll 8
    for (int k = 0; k < HID; ++k) {
        float xv  = __shfl(xk, k, 32);
        float lxv = __shfl(lxk, k, 32);
        float hv  = __shfl(hk, k, 32);
        float lhv = __shfl(lhk, k, 32);
        int row = k * HID + j;
        pre0 += xv * Wx[0 * 2048 + row] + lxv * Wx[0 * 2048 + 1024 + row]
              + hv * Wh[0 * 2048 + row] + lhv * Wh[0 * 2048 + 1024 + row];
        pre1 += xv * Wx[1 * 2048 + row] + lxv * Wx[1 * 2048 + 1024 + row]
              + hv * Wh[1 * 2048 + row] + lhv * Wh[1 * 2048 + 1024 + row];
        pre2 += xv * Wx[2 * 2048 + row] + lxv * Wx[2 * 2048 + 1024 + row]
              + hv * Wh[2 * 2048 + row] + lhv * Wh[2 * 2048 + 1024 + row];
        pre3 += xv * Wx[3 * 2048 + row] + lxv * Wx[3 * 2048 + 1024 + row]
              + hv * Wh[3 * 2048 + row] + lhv * Wh[3 * 2048 + 1024 + row];
    }

    float c0v = C0[base + j];
    float I  = sigmoidf_(pre0 + wc[0 * HID + j] * c0v);
    float Fg = sigmoidf_(pre1 + wc[1 * HID + j] * c0v);
    float T  = tanhf(pre2);
    float C  = Fg * c0v + I * T;
    float O  = sigmoidf_(pre3 + wc[2 * HID + j] * C);
    float H  = O * tanhf(C);

    outH[base + j] = H;
    outC[base + j] = C;
}

// h[n,t] = b_lin[t] + sum_k relu(H[n,k]) * W_lin[k,t]
__global__ void k_head(const float* __restrict__ H, const float* __restrict__ Wl,
                       const float* __restrict__ bl, float* __restrict__ hout, int N) {
    int tid = blockIdx.x * 256 + threadIdx.x;
    int n = tid / HOR;
    int t = tid - n * HOR;
    if (n >= N) return;
    float acc = bl[t];
    #pragma unroll
    for (int k = 0; k < HID; ++k) {
        float v = H[(n << 5) + k];
        acc += fmaxf(v, 0.0f) * Wl[k * HOR + t];
    }
    hout[n * HOR + t] = acc;
}

extern "C" void kernel_launch(void* const* d_in, const int* in_sizes, int n_in,
                              void* d_out, int out_size, void* d_ws, size_t ws_size,
                              hipStream_t stream) {
    const float* x  = (const float*)d_in[0];
    const int*   ei = (const int*)d_in[1];
    const float* ew = (const float*)d_in[2];
    const float* Wx = (const float*)d_in[3];
    const float* bx = (const float*)d_in[4];
    const float* Wh = (const float*)d_in[5];
    const float* bh = (const float*)d_in[6];
    const float* wc = (const float*)d_in[7];
    const float* b  = (const float*)d_in[8];
    const float* Wl = (const float*)d_in[9];
    const float* bl = (const float*)d_in[10];
    const float* h0 = (const float*)d_in[11];
    const float* c0 = (const float*)d_in[12];

    int N = in_sizes[0] / HID;      // x is (N,1,32)
    int E = in_sizes[2];            // edge_weight is (E,)
    const int* src = ei;
    const int* dst = ei + E;
    int nbk = (N + BNODES - 1) >> BSH;          // 1563 for N=50000 (< MAXBK)
    int chunk = (E + NBLK - 1) / NBLK;

    // workspace (int units):
    // [dstBins 2E][srcBins region: max(2E, 2*N*32) — srcBins aliased by LX/LH]
    // [histS NBLK*nbk][histD NBLK*nbk][totS MAXBK][totD MAXBK]
    // [baseS MAXBK+1][baseD MAXBK+1][dinv N][flag 1]
    int* wsi = (int*)d_ws;
    size_t regionB = (size_t)2 * E;
    size_t regionL = (size_t)2 * N * HID;
    size_t region  = regionB > regionL ? regionB : regionL;

    int2*  dstBins = (int2*)wsi;
    int2*  srcBins = (int2*)(wsi + (size_t)2 * E);
    float* LX      = (float*)srcBins;                // aliases srcBins (dead after k_deg)
    float* LH      = LX + (size_t)N * HID;
    int*   histS   = wsi + (size_t)2 * E + region;
    int*   histD   = histS + (size_t)NBLK * nbk;
    int*   totS    = histD + (size_t)NBLK * nbk;
    int*   totD    = totS + MAXBK;
    int*   baseS   = totD + MAXBK;
    int*   baseD   = baseS + (MAXBK + 1);
    float* dinv    = (float*)(baseD + (MAXBK + 1));
    int*   flag    = (int*)(dinv + N);

    float* hOut = (float*)d_out;            // (N,12)
    float* HOut = hOut + (size_t)N * HOR;   // (N,32)
    float* COut = HOut + (size_t)N * HID;   // (N,32)

    hipMemsetAsync(flag, 0, sizeof(int), stream);

    k_count<<<NBLK, 256, 0, stream>>>(src, dst, E, chunk, nbk, histS, histD);
    k_colscan<<<2 * ((nbk + 255) / 256), 256, 0, stream>>>(histS, histD, totS, totD, nbk);
    k_bucketbase<<<1, 256, 0, stream>>>(totS, totD, baseS, baseD, nbk);
    k_hflag<<<(N * HID + 255) / 256, 256, 0, stream>>>(h0, flag, N * HID);

    k_scatter2<<<NBLK, 256, 0, stream>>>(src, dst, ew, E, chunk, nbk,
                                         histS, histD, baseS, baseD, srcBins, dstBins);

    k_deg<<<nbk, 256, 0, stream>>>(srcBins, baseS, dinv, N);

    k_fold<<<(E + 255) / 256, 256, 0, stream>>>(dstBins, dinv, E);

    k_acc<<<nbk, 256, 0, stream>>>(dstBins, baseD, dinv, x, h0, flag, LX, LH, N);

    k_gates<<<(N * HID + 255) / 256, 256, 0, stream>>>(x, LX, h0, LH, c0,
                                                       Wx, bx, Wh, bh, wc, b,
                                                       HOut, COut, N);

    k_head<<<(N * HOR + 255) / 256, 256, 0, stream>>>(HOut, Wl, bl, hOut, N);
}

// Round 8
// 599.382 us; speedup vs baseline: 1.0955x; 1.0491x over previous
//
#include <hip/hip_runtime.h>
#include <math.h>

#define HID 32
#define HOR 12
#define NBLK 128          // edge-chunk blocks for count/scatter
#define BSH 5             // 32 nodes per bucket
#define BNODES 32
#define MAXBK 2048        // max buckets (requires N <= 65536 and nbk <= MAXBK)
#define LSTR 33           // LDS row stride (+1 pad)
#define GY 8              // chunk-slot grid height (stride loop covers bigger buckets)

__device__ __forceinline__ float sigmoidf_(float x) { return 1.0f / (1.0f + expf(-x)); }

// K1: per-chunk histograms by src-bucket and dst-bucket (LDS atomics only)
__global__ __launch_bounds__(256) void k_count(const int* __restrict__ src,
    const int* __restrict__ dst, int E, int chunk, int nbk,
    int* __restrict__ histS, int* __restrict__ histD) {
    __shared__ int hs[MAXBK], hd[MAXBK];
    int t = threadIdx.x;
    for (int c = t; c < nbk; c += 256) { hs[c] = 0; hd[c] = 0; }
    __syncthreads();
    int beg = blockIdx.x * chunk, end = min(beg + chunk, E);
    for (int i = beg + t; i < end; i += 256) {
        atomicAdd(&hs[src[i] >> BSH], 1);
        atomicAdd(&hd[dst[i] >> BSH], 1);
    }
    __syncthreads();
    size_t rb = (size_t)blockIdx.x * nbk;
    for (int c = t; c < nbk; c += 256) { histS[rb + c] = hs[c]; histD[rb + c] = hd[c]; }
}

// K2a: in-place column exclusive prefix over chunk-blocks; emit column totals
__global__ void k_colscan(int* __restrict__ histS, int* __restrict__ histD,
                          int* __restrict__ totS, int* __restrict__ totD, int nbk) {
    int table = blockIdx.x & 1;
    int col = (blockIdx.x >> 1) * 256 + threadIdx.x;
    if (col >= nbk) return;
    int* h  = table ? histD : histS;
    int* tt = table ? totD : totS;
    int run = 0;
    for (int b = 0; b < NBLK; ++b) {
        size_t idx = (size_t)b * nbk + col;
        int v = h[idx]; h[idx] = run; run += v;
    }
    tt[col] = run;
}

// K2b: exclusive scan of bucket totals -> baseS/baseD (nbk+1 entries each)
__global__ __launch_bounds__(256) void k_bucketbase(const int* __restrict__ totS,
    const int* __restrict__ totD, int* __restrict__ baseS, int* __restrict__ baseD, int nbk) {
    __shared__ int ss[256];
    int t = threadIdx.x;
    for (int table = 0; table < 2; ++table) {
        const int* tot = table ? totD : totS;
        int* base = table ? baseD : baseS;
        int a[8]; int tsum = 0;
        #pragma unroll
        for (int k2 = 0; k2 < 8; ++k2) {
            int i = t * 8 + k2;
            a[k2] = (i < nbk) ? tot[i] : 0;
            tsum += a[k2];
        }
        ss[t] = tsum; __syncthreads();
        for (int off = 1; off < 256; off <<= 1) {
            int v = (t >= off) ? ss[t - off] : 0;
            __syncthreads(); ss[t] += v; __syncthreads();
        }
        int run = ss[t] - tsum;
        #pragma unroll
        for (int k2 = 0; k2 < 8; ++k2) {
            int i = t * 8 + k2;
            if (i <= nbk) base[i] = run;
            run += a[k2];
        }
        __syncthreads();
    }
}

// flag = 1 if any h0 element nonzero
__global__ void k_hflag(const float* __restrict__ h0, int* __restrict__ flag, int total) {
    int i = blockIdx.x * 256 + threadIdx.x;
    float v = (i < total) ? h0[i] : 0.0f;
    if (__ballot(v != 0.0f)) {
        if ((threadIdx.x & 63) == 0) atomicOr(flag, 1);
    }
}

// K3: scatter edges into exact reserved slots; LDS cursors only, plain global stores
__global__ __launch_bounds__(256) void k_scatter2(const int* __restrict__ src,
    const int* __restrict__ dst, const float* __restrict__ w, int E, int chunk, int nbk,
    const int* __restrict__ histS, const int* __restrict__ histD,
    const int* __restrict__ baseS, const int* __restrict__ baseD,
    int2* __restrict__ srcBins, int2* __restrict__ dstBins) {
    __shared__ int curS[MAXBK], curD[MAXBK];
    int t = threadIdx.x;
    size_t rb = (size_t)blockIdx.x * nbk;
    for (int c = t; c < nbk; c += 256) {
        curS[c] = baseS[c] + histS[rb + c];
        curD[c] = baseD[c] + histD[rb + c];
    }
    __syncthreads();
    int beg = blockIdx.x * chunk, end = min(beg + chunk, E);
    for (int i = beg + t; i < end; i += 256) {
        int s = src[i], d = dst[i];
        float wv = w[i];
        int ps = atomicAdd(&curS[s >> BSH], 1);
        srcBins[ps] = make_int2(s, __float_as_int(wv));
        int pd = atomicAdd(&curD[d >> BSH], 1);
        dstBins[pd] = make_int2(s | ((d & (BNODES - 1)) << 16), __float_as_int(wv));
    }
}

// K4: per src-bucket: deg in LDS (ds_add_f32) -> dinv coalesced
__global__ __launch_bounds__(256) void k_deg(const int2* __restrict__ srcBins,
    const int* __restrict__ baseS, float* __restrict__ dinv, int N) {
    __shared__ float dg[BNODES];
    int t = threadIdx.x, b = blockIdx.x;
    if (t < BNODES) dg[t] = 0.0f;
    __syncthreads();
    int beg = baseS[b], end = baseS[b + 1];
    for (int i = beg + t; i < end; i += 256) {
        int2 r = srcBins[i];
        atomicAdd(&dg[r.x & (BNODES - 1)], __int_as_float(r.y));
    }
    __syncthreads();
    if (t < BNODES) {
        int n = (b << BSH) + t;
        if (n < N) { float s = dg[t]; dinv[n] = (s > 0.0f) ? rsqrtf(s) : 0.0f; }
    }
}

// K5: flat streaming: dstBins.y <- -w * dinv[src] (dinv is L2-resident)
__global__ __launch_bounds__(256) void k_fold(int2* __restrict__ dstBins,
    const float* __restrict__ dinv, int E) {
    int e = blockIdx.x * 256 + threadIdx.x;
    if (e >= E) return;
    int2 r = dstBins[e];
    float nws = -__int_as_float(r.y) * dinv[r.x & 0xFFFF];
    dstBins[e].y = __float_as_int(nws);
}

// K6: ONE BLOCK PER 256-EDGE CHUNK (2-D grid: bucket x chunk-slot, stride GY).
// Each chunk-block builds a partial 32x32 tile in LDS (8 independent float4
// X-row loads per thread), then flushes into zeroed LX/LH with global
// atomicAdd, folding dinv[dst]. ~6250 independent latency chains vs 1563
// serial-loop blocks in R7.
__global__ __launch_bounds__(256) void k_acc(const int2* __restrict__ dstBins,
    const int* __restrict__ baseD, const float* __restrict__ dinv,
    const float* __restrict__ X, const float* __restrict__ H0,
    const int* __restrict__ hflag,
    float* __restrict__ LX, float* __restrict__ LH, int N) {
    __shared__ float lx[BNODES * LSTR];
    __shared__ float lh[BNODES * LSTR];
    __shared__ int2  rec[256];
    int t = threadIdx.x, b = blockIdx.x;
    int beg = baseD[b], end = baseD[b + 1];
    int cs0 = beg + (int)blockIdx.y * 256;
    if (cs0 >= end) return;                      // block-uniform early out

    for (int i = t; i < BNODES * LSTR; i += 256) { lx[i] = 0.0f; lh[i] = 0.0f; }
    bool hf = (*hflag != 0);
    const float4* X4 = (const float4*)X;
    const float4* H4 = (const float4*)H0;
    int slot = t >> 3;          // 0..31 edge slot
    int qi = t & 7;             // feature quad
    int fb = qi << 2;           // feature base

    for (int cs = cs0; cs < end; cs += GY * 256) {
        int m = end - cs; if (m > 256) m = 256;
        __syncthreads();                          // protect rec[] + tiles
        if (t < m) rec[t] = dstBins[cs + t];
        __syncthreads();

        int2 r[8]; bool val[8];
        #pragma unroll
        for (int p = 0; p < 8; ++p) {
            int ei = (p << 5) + slot;
            val[p] = ei < m;
            r[p] = val[p] ? rec[ei] : make_int2(0, 0);
        }
        float4 xv[8];
        #pragma unroll
        for (int p = 0; p < 8; ++p) {
            int s = r[p].x & 0xFFFF;
            xv[p] = val[p] ? X4[(s << 3) + qi] : make_float4(0.f, 0.f, 0.f, 0.f);
        }
        if (hf) {
            float4 hv[8];
            #pragma unroll
            for (int p = 0; p < 8; ++p) {
                int s = r[p].x & 0xFFFF;
                hv[p] = val[p] ? H4[(s << 3) + qi] : make_float4(0.f, 0.f, 0.f, 0.f);
            }
            #pragma unroll
            for (int p = 0; p < 8; ++p) {
                if (val[p]) {
                    float w = __int_as_float(r[p].y);
                    int lb = (r[p].x >> 16) * LSTR + fb;
                    atomicAdd(&lx[lb + 0], w * xv[p].x);
                    atomicAdd(&lx[lb + 1], w * xv[p].y);
                    atomicAdd(&lx[lb + 2], w * xv[p].z);
                    atomicAdd(&lx[lb + 3], w * xv[p].w);
                    atomicAdd(&lh[lb + 0], w * hv[p].x);
                    atomicAdd(&lh[lb + 1], w * hv[p].y);
                    atomicAdd(&lh[lb + 2], w * hv[p].z);
                    atomicAdd(&lh[lb + 3], w * hv[p].w);
                }
            }
        } else {
            #pragma unroll
            for (int p = 0; p < 8; ++p) {
                if (val[p]) {
                    float w = __int_as_float(r[p].y);
                    int lb = (r[p].x >> 16) * LSTR + fb;
                    atomicAdd(&lx[lb + 0], w * xv[p].x);
                    atomicAdd(&lx[lb + 1], w * xv[p].y);
                    atomicAdd(&lx[lb + 2], w * xv[p].z);
                    atomicAdd(&lx[lb + 3], w * xv[p].w);
                }
            }
        }
    }
    __syncthreads();

    // flush partial tile into global LX/LH (zero-initialized), folding dinv[dst]
    for (int i = t; i < BNODES * HID; i += 256) {
        int dl = i >> 5, f = i & 31;
        int n = (b << BSH) + dl;
        if (n < N) {
            float dvv = dinv[n];
            float vx = lx[dl * LSTR + f];
            if (vx != 0.0f) atomicAdd(&LX[(n << 5) + f], dvv * vx);
            if (hf) {
                float vh = lh[dl * LSTR + f];
                if (vh != 0.0f) atomicAdd(&LH[(n << 5) + f], dvv * vh);
            }
        }
    }
}

// Per (node n, out-feature j): 4 gates fused LSTM cell
__global__ __launch_bounds__(256) void k_gates(
    const float* __restrict__ X, const float* __restrict__ LX,
    const float* __restrict__ H0, const float* __restrict__ LH,
    const float* __restrict__ C0,
    const float* __restrict__ Wx, const float* __restrict__ bx,
    const float* __restrict__ Wh, const float* __restrict__ bh,
    const float* __restrict__ wc, const float* __restrict__ b,
    float* __restrict__ outH, float* __restrict__ outC, int N) {
    int tid = blockIdx.x * 256 + threadIdx.x;
    int n = tid >> 5;
    int j = tid & 31;
    if (n >= N) return;

    int base = n << 5;
    float xk  = X[base + j];
    float lxk = LX[base + j];
    float hk  = H0[base + j];
    float lhk = LH[base + j];

    float pre0 = bx[0 * HID + j] + bh[0 * HID + j] + b[0 * HID + j];
    float pre1 = bx[1 * HID + j] + bh[1 * HID + j] + b[1 * HID + j];
    float pre2 = bx[2 * HID + j] + bh[2 * HID + j] + b[2 * HID + j];
    float pre3 = bx[3 * HID + j] + bh[3 * HID + j] + b[3 * HID + j];

    #pragma unroll 8
    for (int k = 0; k < HID; ++k) {
        float xv  = __shfl(xk, k, 32);
        float lxv = __shfl(lxk, k, 32);
        float hv  = __shfl(hk, k, 32);
        float lhv = __shfl(lhk, k, 32);
        int row = k * HID + j;
        pre0 += xv * Wx[0 * 2048 + row] + lxv * Wx[0 * 2048 + 1024 + row]
              + hv * Wh[0 * 2048 + row] + lhv * Wh[0 * 2048 + 1024 + row];
        pre1 += xv * Wx[1 * 2048 + row] + lxv * Wx[1 * 2048 + 1024 + row]
              + hv * Wh[1 * 2048 + row] + lhv * Wh[1 * 2048 + 1024 + row];
        pre2 += xv * Wx[2 * 2048 + row] + lxv * Wx[2 * 2048 + 1024 + row]
              + hv * Wh[2 * 2048 + row] + lhv * Wh[2 * 2048 + 1024 + row];
        pre3 += xv * Wx[3 * 2048 + row] + lxv * Wx[3 * 2048 + 1024 + row]
              + hv * Wh[3 * 2048 + row] + lhv * Wh[3 * 2048 + 1024 + row];
    }

    float c0v = C0[base + j];
    float I  = sigmoidf_(pre0 + wc[0 * HID + j] * c0v);
    float Fg = sigmoidf_(pre1 + wc[1 * HID + j] * c0v);
    float T  = tanhf(pre2);
    float C  = Fg * c0v + I * T;
    float O  = sigmoidf_(pre3 + wc[2 * HID + j] * C);
    float H  = O * tanhf(C);

    outH[base + j] = H;
    outC[base + j] = C;
}

// h[n,t] = b_lin[t] + sum_k relu(H[n,k]) * W_lin[k,t]
__global__ void k_head(const float* __restrict__ H, const float* __restrict__ Wl,
                       const float* __restrict__ bl, float* __restrict__ hout, int N) {
    int tid = blockIdx.x * 256 + threadIdx.x;
    int n = tid / HOR;
    int t = tid - n * HOR;
    if (n >= N) return;
    float acc = bl[t];
    #pragma unroll
    for (int k = 0; k < HID; ++k) {
        float v = H[(n << 5) + k];
        acc += fmaxf(v, 0.0f) * Wl[k * HOR + t];
    }
    hout[n * HOR + t] = acc;
}

extern "C" void kernel_launch(void* const* d_in, const int* in_sizes, int n_in,
                              void* d_out, int out_size, void* d_ws, size_t ws_size,
                              hipStream_t stream) {
    const float* x  = (const float*)d_in[0];
    const int*   ei = (const int*)d_in[1];
    const float* ew = (const float*)d_in[2];
    const float* Wx = (const float*)d_in[3];
    const float* bx = (const float*)d_in[4];
    const float* Wh = (const float*)d_in[5];
    const float* bh = (const float*)d_in[6];
    const float* wc = (const float*)d_in[7];
    const float* b  = (const float*)d_in[8];
    const float* Wl = (const float*)d_in[9];
    const float* bl = (const float*)d_in[10];
    const float* h0 = (const float*)d_in[11];
    const float* c0 = (const float*)d_in[12];

    int N = in_sizes[0] / HID;      // x is (N,1,32)
    int E = in_sizes[2];            // edge_weight is (E,)
    const int* src = ei;
    const int* dst = ei + E;
    int nbk = (N + BNODES - 1) >> BSH;          // 1563 for N=50000 (< MAXBK)
    int chunk = (E + NBLK - 1) / NBLK;

    // workspace (int units):
    // [dstBins 2E][srcBins region: max(2E, 2*N*32) — srcBins aliased by LX/LH]
    // [histS NBLK*nbk][histD NBLK*nbk][totS MAXBK][totD MAXBK]
    // [baseS MAXBK+1][baseD MAXBK+1][dinv N][flag 1]
    int* wsi = (int*)d_ws;
    size_t regionB = (size_t)2 * E;
    size_t regionL = (size_t)2 * N * HID;
    size_t region  = regionB > regionL ? regionB : regionL;

    int2*  dstBins = (int2*)wsi;
    int2*  srcBins = (int2*)(wsi + (size_t)2 * E);
    float* LX      = (float*)srcBins;                // aliases srcBins (dead after k_deg)
    float* LH      = LX + (size_t)N * HID;
    int*   histS   = wsi + (size_t)2 * E + region;
    int*   histD   = histS + (size_t)NBLK * nbk;
    int*   totS    = histD + (size_t)NBLK * nbk;
    int*   totD    = totS + MAXBK;
    int*   baseS   = totD + MAXBK;
    int*   baseD   = baseS + (MAXBK + 1);
    float* dinv    = (float*)(baseD + (MAXBK + 1));
    int*   flag    = (int*)(dinv + N);

    float* hOut = (float*)d_out;            // (N,12)
    float* HOut = hOut + (size_t)N * HOR;   // (N,32)
    float* COut = HOut + (size_t)N * HID;   // (N,32)

    hipMemsetAsync(flag, 0, sizeof(int), stream);

    k_count<<<NBLK, 256, 0, stream>>>(src, dst, E, chunk, nbk, histS, histD);
    k_colscan<<<2 * ((nbk + 255) / 256), 256, 0, stream>>>(histS, histD, totS, totD, nbk);
    k_bucketbase<<<1, 256, 0, stream>>>(totS, totD, baseS, baseD, nbk);
    k_hflag<<<(N * HID + 255) / 256, 256, 0, stream>>>(h0, flag, N * HID);

    k_scatter2<<<NBLK, 256, 0, stream>>>(src, dst, ew, E, chunk, nbk,
                                         histS, histD, baseS, baseD, srcBins, dstBins);

    k_deg<<<nbk, 256, 0, stream>>>(srcBins, baseS, dinv, N);

    // LX/LH alias srcBins (dead after k_deg); zero them for atomic flush
    hipMemsetAsync(LX, 0, 2 * (size_t)N * HID * sizeof(float), stream);

    k_fold<<<(E + 255) / 256, 256, 0, stream>>>(dstBins, dinv, E);

    dim3 accGrid(nbk, GY);
    k_acc<<<accGrid, 256, 0, stream>>>(dstBins, baseD, dinv, x, h0, flag, LX, LH, N);

    k_gates<<<(N * HID + 255) / 256, 256, 0, stream>>>(x, LX, h0, LH, c0,
                                                       Wx, bx, Wh, bh, wc, b,
                                                       HOut, COut, N);

    k_head<<<(N * HOR + 255) / 256, 256, 0, stream>>>(HOut, Wl, bl, hOut, N);
}